// Round 6
// baseline (490.480 us; speedup 1.0000x reference)
//
#include <hip/hip_runtime.h>
#include <hip/hip_bf16.h>
#include <stdint.h>

#define TWO_N  8192
#define NHALF  4096
#define DDIM   256
#define MARGIN 0.5f
#define NTRI   2080   // 64*65/2 upper-triangle tile pairs

// ---- workspace layout (bytes) ----
static const size_t OFF_EMB  = 0;                            // 8192*256 bf16 = 4 MB
static const size_t OFF_X2   = 4u * 1024 * 1024;             // 8192 f32
static const size_t OFF_AP   = OFF_X2 + (size_t)TWO_N * 4;   // 4096 f32
static const size_t OFF_FLAG = OFF_AP + (size_t)NHALF * 4;   // 1 int (padded)
static const size_t OFF_PART = OFF_FLAG + 256;               // 64 * 8192 f32 = 2 MB
static const size_t OFF_RS   = OFF_PART + 64ull * TWO_N * 4; // 8192 f32

typedef __attribute__((ext_vector_type(8))) short bf16x8;
typedef __attribute__((ext_vector_type(4))) float f32x4;

__device__ inline ushort f2bf(float f) {
  uint32_t u = __float_as_uint(f);
  uint32_t r = (u + 0x7FFFu + ((u >> 16) & 1u)) >> 16;  // RNE
  return (ushort)r;
}
__device__ inline float bf2f(ushort h) { return __uint_as_float((uint32_t)h << 16); }

// async global->LDS, 16B per lane; LDS dest = wave-uniform base + lane*16
__device__ inline void gload_lds16(const void* g, void* l) {
  __builtin_amdgcn_global_load_lds(
      (const __attribute__((address_space(1))) uint32_t*)(uintptr_t)g,
      (__attribute__((address_space(3))) uint32_t*)(uint32_t)(uintptr_t)l,
      16, 0, 0);
}

#define STR2(x) #x
#define WAITVM(N) asm volatile("s_waitcnt vmcnt(" STR2(N) ")" ::: "memory")

// ---------------- prep: bf16 convert + x2 (from bf16 values) + mask-dtype detect ----------------
__global__ __launch_bounds__(256) void smv2_prep(
    const float* __restrict__ emb,
    const uint32_t* __restrict__ maskw,
    ushort* __restrict__ emb_bf,
    float* __restrict__ x2,
    int* __restrict__ flag)
{
  const int t = threadIdx.x;
  if (blockIdx.x == 0) {
    __shared__ int sflag;
    if (t == 0) sflag = 0;
    __syncthreads();
    int found = 0;
    #pragma unroll
    for (int k = 0; k < 8; ++k) {
      uint32_t w = maskw[t * 8 + k];
      if (w > 1u && (w & 0xFEFEFEFEu) == 0u) found = 1;  // bytes in {0,1} => byte mask
    }
    if (found) atomicOr(&sflag, 1);
    __syncthreads();
    if (t == 0) *flag = sflag;
  }
  const int row  = blockIdx.x * 8 + (t >> 5);
  const int lane = t & 31;
  const float* rp = emb + (size_t)row * DDIM + lane * 8;
  float4 v0 = *(const float4*)(rp);
  float4 v1 = *(const float4*)(rp + 4);
  float vals[8] = {v0.x, v0.y, v0.z, v0.w, v1.x, v1.y, v1.z, v1.w};
  uint32_t packed[4];
  float ss = 0.f;
  #pragma unroll
  for (int k = 0; k < 4; ++k) {
    ushort h0 = f2bf(vals[2 * k]);
    ushort h1 = f2bf(vals[2 * k + 1]);
    packed[k] = (uint32_t)h0 | ((uint32_t)h1 << 16);
    float f0 = bf2f(h0), f1 = bf2f(h1);
    ss += f0 * f0 + f1 * f1;
  }
  *(uint4*)(emb_bf + (size_t)row * DDIM + lane * 8) =
      make_uint4(packed[0], packed[1], packed[2], packed[3]);
  #pragma unroll
  for (int m = 1; m < 32; m <<= 1) ss += __shfl_xor(ss, m);
  if (lane == 0) x2[row] = ss;
}

// ---------------- main: symmetric fused Gram -> dist -> exp -> masked row+col partials ----------
// Upper-triangle tile pairs (by<=bx), 512 threads (8 waves 2x4), tile 128x128.
// 8 K-phases of 32 (64B rows), TRIPLE-buffered A/B tiles, counted-vmcnt pipeline
// (raw s_barrier; prefetch depth 2; vmcnt never drained to 0 until the last phase).
// LDS: 3*(8K+8K) + M1 16K + x2 1K = 65KB -> 2 blocks/CU.
__global__ __launch_bounds__(512, 4) void smv2_main(
    const ushort* __restrict__ emb_bf,
    const float* __restrict__ x2,
    const uint8_t* __restrict__ mask8,
    const int* __restrict__ flagp,
    float* __restrict__ ap,
    float* __restrict__ partial)
{
  __shared__ char bufA[3 * 8192];
  __shared__ char bufB[3 * 8192];
  __shared__ uint8_t ldsM[128 * 128];
  __shared__ float ldsX[256];          // x2[brow..+128) | x2[bcol..+128)

  const int t = threadIdx.x;

  // XCD chunking (2080 = 8*260) + triangular decode (bx-outer: B panel stable per XCD)
  const int bid = blockIdx.x;
  const int idx = (bid & 7) * (NTRI / 8) + (bid >> 3);
  float rf = sqrtf(8.f * (float)idx + 1.f);
  int bx = (int)((rf - 1.f) * 0.5f);
  while ((bx + 1) * (bx + 2) / 2 <= idx) ++bx;
  while (bx * (bx + 1) / 2 > idx) --bx;
  const int by = idx - bx * (bx + 1) / 2;  // by <= bx
  const int brow = by * 128;
  const int bcol = bx * 128;
  const bool diag = (bx == by);

  const char* gA = (const char*)(emb_bf + (size_t)brow * DDIM);  // 512B rows
  const char* gB = (const char*)(emb_bf + (size_t)bcol * DDIM);

  // ---- hoisted staging addresses (phase adds +64 on the global side) ----
  const int srow = t >> 2;                       // 0..127
  const int scb  = ((t & 3) * 16) ^ (((srow >> 1) & 3) << 4);  // pre-swizzled col
  const size_t gAoff = (size_t)srow * 512 + scb;
  const size_t gBoff = gAoff;                    // same row geometry
  const int ldst = t * 16;

  const int w  = t >> 6;
  const int l  = t & 63;
  const int wr = w >> 2;           // wave row 0..1  (64 rows)
  const int wc = w & 3;            // wave col 0..3  (32 cols)
  const int cl = l & 15;
  const int kh = l >> 4;

  // ---- hoisted ds_read offsets (bank-swizzled: ((row>>1)&3)<<4 on 64B rows) ----
  int aoff[4], boff[2];
  #pragma unroll
  for (int m = 0; m < 4; ++m) {
    const int row = wr * 64 + m * 16 + cl;
    aoff[m] = row * 64 + ((kh * 16) ^ (((row >> 1) & 3) << 4));
  }
  #pragma unroll
  for (int n = 0; n < 2; ++n) {
    const int row = wc * 32 + n * 16 + cl;
    boff[n] = row * 64 + ((kh * 16) ^ (((row >> 1) & 3) << 4));
  }

  f32x4 acc[4][2];
  #pragma unroll
  for (int m = 0; m < 4; ++m)
    #pragma unroll
    for (int n = 0; n < 2; ++n) {
      f32x4 z = {0.f, 0.f, 0.f, 0.f};
      acc[m][n] = z;
    }
  uint32_t m2r[2][4];

#define STAGE(Q)                                                            \
  {                                                                         \
    gload_lds16(gA + gAoff + (Q) * 64, bufA + ((Q) % 3) * 8192 + ldst);     \
    gload_lds16(gB + gBoff + (Q) * 64, bufB + ((Q) % 3) * 8192 + ldst);     \
  }

#define M2LOAD                                                              \
  {                                                                         \
    _Pragma("unroll")                                                       \
    for (int n = 0; n < 2; ++n) {                                           \
      const int gj = bcol + wc * 32 + n * 16 + cl;                          \
      _Pragma("unroll")                                                     \
      for (int m = 0; m < 4; ++m)                                           \
        m2r[n][m] = *(const uint32_t*)(mask8 + (size_t)gj * TWO_N + brow +  \
                                       wr * 64 + m * 16 + kh * 4);          \
    }                                                                       \
  }

#define COMPUTE(P)                                                          \
  {                                                                         \
    const char* ba = bufA + ((P) % 3) * 8192;                               \
    const char* bb = bufB + ((P) % 3) * 8192;                               \
    bf16x8 a0 = *(const bf16x8*)(ba + aoff[0]);                             \
    bf16x8 a1 = *(const bf16x8*)(ba + aoff[1]);                             \
    bf16x8 a2 = *(const bf16x8*)(ba + aoff[2]);                             \
    bf16x8 a3 = *(const bf16x8*)(ba + aoff[3]);                             \
    bf16x8 b0 = *(const bf16x8*)(bb + boff[0]);                             \
    bf16x8 b1 = *(const bf16x8*)(bb + boff[1]);                             \
    acc[0][0] = __builtin_amdgcn_mfma_f32_16x16x32_bf16(a0, b0, acc[0][0], 0, 0, 0); \
    acc[0][1] = __builtin_amdgcn_mfma_f32_16x16x32_bf16(a0, b1, acc[0][1], 0, 0, 0); \
    acc[1][0] = __builtin_amdgcn_mfma_f32_16x16x32_bf16(a1, b0, acc[1][0], 0, 0, 0); \
    acc[1][1] = __builtin_amdgcn_mfma_f32_16x16x32_bf16(a1, b1, acc[1][1], 0, 0, 0); \
    acc[2][0] = __builtin_amdgcn_mfma_f32_16x16x32_bf16(a2, b0, acc[2][0], 0, 0, 0); \
    acc[2][1] = __builtin_amdgcn_mfma_f32_16x16x32_bf16(a2, b1, acc[2][1], 0, 0, 0); \
    acc[3][0] = __builtin_amdgcn_mfma_f32_16x16x32_bf16(a3, b0, acc[3][0], 0, 0, 0); \
    acc[3][1] = __builtin_amdgcn_mfma_f32_16x16x32_bf16(a3, b1, acc[3][1], 0, 0, 0); \
  }

#define PHASE(P, NW, SQ, DOM2)                                              \
  {                                                                         \
    WAITVM(NW);                                                             \
    __builtin_amdgcn_s_barrier();                                           \
    __builtin_amdgcn_sched_barrier(0);                                      \
    if ((SQ) >= 0) STAGE((SQ) < 0 ? 0 : (SQ));                              \
    if (DOM2) M2LOAD;                                                       \
    __builtin_amdgcn_sched_barrier(0);                                      \
    COMPUTE(P);                                                             \
  }

  // ---- prologue issue (queue: s0,s0, s1,s1, M1,M1, x2) ----
  STAGE(0);
  STAGE(1);
  #pragma unroll
  for (int it = 0; it < 2; ++it) {   // mask M1 tile, row-swizzled ((r>>2)&3)<<5
    const int dl   = it * 8192 + t * 16;
    const int mrow = dl >> 7;
    const int mc   = dl & 127;
    const int msw  = ((mrow >> 2) & 3) << 5;
    gload_lds16(mask8 + (size_t)(brow + mrow) * TWO_N + bcol + (mc ^ msw), ldsM + dl);
  }
  {  // x2 slices: every wave issues identically (benign duplicate writes)
    const float* src = (l < 32) ? (x2 + brow + l * 4) : (x2 + bcol + (l - 32) * 4);
    gload_lds16(src, (char*)ldsX + l * 16);
  }

  // ---- 8-phase counted-vmcnt pipeline ----
  PHASE(0, 5, 2, 0)
  PHASE(1, 5, 3, 0)
  PHASE(2, 2, 4, 0)
  PHASE(3, 2, 5, 1)
  PHASE(4, 10, 6, 0)
  PHASE(5, 10, 7, 0)
  PHASE(6, 2, -1, 0)
  PHASE(7, 0, -1, 0)

  // ---- epilogue ----
  const int isByte = *flagp;
  const uint32_t* maskww = (const uint32_t*)mask8;

  float* part  = (float*)bufA;   // [4][128] row-side partials (buf 0 free: phase 7 uses buf 1)
  float* part2 = (float*)bufB;   // [2][128] col-side partials
  float cs[2] = {0.f, 0.f};

  #pragma unroll
  for (int m = 0; m < 4; ++m) {
    #pragma unroll
    for (int q = 0; q < 4; ++q) {
      const int lrow = wr * 64 + m * 16 + kh * 4 + q;  // C/D: row = (l>>4)*4 + reg
      const int gi = brow + lrow;
      const float xi = ldsX[lrow];
      const int msw = kh << 5;        // ((lrow>>2)&3)<<5 == kh<<5
      float rp = 0.f;
      #pragma unroll
      for (int n = 0; n < 2; ++n) {
        const int jc = wc * 32 + n * 16 + cl;
        const int gj = bcol + jc;
        const float g = acc[m][n][q];
        float sq = (gi == gj) ? 0.f : (xi + ldsX[128 + jc] - 2.f * g);
        sq = fmaxf(sq, 0.f) + 1e-12f;
        const float dd = __builtin_amdgcn_sqrtf(sq);
        if (gj == gi + NHALF && gi < NHALF) ap[gi] = dd;  // anchor-positive distance
        const float e = __expf(MARGIN - dd);
        bool mk1;
        if (isByte) mk1 = ldsM[lrow * 128 + (jc ^ msw)] != 0;
        else        mk1 = maskww[(size_t)gi * TWO_N + gj] != 0u;
        rp += mk1 ? e : 0.f;
        if (!diag) {
          bool mk2;
          if (isByte) mk2 = ((m2r[n][m] >> (8 * q)) & 255u) != 0u;
          else        mk2 = maskww[(size_t)gj * TWO_N + gi] != 0u;
          cs[n] += mk2 ? e : 0.f;
        }
      }
      #pragma unroll
      for (int s = 1; s < 16; s <<= 1) rp += __shfl_xor(rp, s);
      if (cl == 0) part[wc * 128 + lrow] = rp;
    }
  }

  if (!diag) {
    #pragma unroll
    for (int n = 0; n < 2; ++n) {
      cs[n] += __shfl_xor(cs[n], 16);   // reduce over kh
      cs[n] += __shfl_xor(cs[n], 32);
      if (l < 16) part2[wr * 128 + wc * 32 + n * 16 + l] = cs[n];
    }
  }
  __syncthreads();

  if (t < 128) {
    partial[(size_t)bx * TWO_N + brow + t] =
        (part[t] + part[128 + t]) + (part[256 + t] + part[384 + t]);
    if (!diag)
      partial[(size_t)by * TWO_N + bcol + t] = part2[t] + part2[128 + t];
  }
#undef PHASE
#undef COMPUTE
#undef M2LOAD
#undef STAGE
}

// ---------------- row sums: rs[i] = sum over 64 col-tiles ----------------
__global__ __launch_bounds__(256) void smv2_rowsum(
    const float* __restrict__ partial, float* __restrict__ rs)
{
  const int row = blockIdx.x * 256 + threadIdx.x;
  float s = 0.f;
  #pragma unroll 8
  for (int b = 0; b < 64; ++b) s += partial[(size_t)b * TWO_N + row];
  rs[row] = s;
}

// ---------------- finalize: j = log(rs[i]+rs[i+N]) + ap[i]; loss ----------------
__global__ __launch_bounds__(1024) void smv2_finalize(
    const float* __restrict__ rs, const float* __restrict__ ap,
    float* __restrict__ out)
{
  const int t = threadIdx.x;
  float sum = 0.f, cnt = 0.f;
  for (int i = t; i < NHALF; i += 1024) {
    float rsum = rs[i] + rs[i + NHALF];
    float jv = logf(rsum) + ap[i];
    if (!isnan(jv)) {
      cnt += 1.f;
      float mj = fmaxf(jv, 0.f);
      sum += mj * mj;
    }
  }
  __shared__ float ssum[16], scnt[16];
  #pragma unroll
  for (int s = 32; s >= 1; s >>= 1) {
    sum += __shfl_down(sum, s);
    cnt += __shfl_down(cnt, s);
  }
  const int wid = t >> 6, lid = t & 63;
  if (lid == 0) { ssum[wid] = sum; scnt[wid] = cnt; }
  __syncthreads();
  if (t == 0) {
    float S = 0.f, C = 0.f;
    #pragma unroll
    for (int i = 0; i < 16; ++i) { S += ssum[i]; C += scnt[i]; }
    if (C < 1.f) C = 1.f;
    out[0] = S / C * 0.5f;
  }
}

extern "C" void kernel_launch(void* const* d_in, const int* in_sizes, int n_in,
                              void* d_out, int out_size, void* d_ws, size_t ws_size,
                              hipStream_t stream) {
  const float* emb = (const float*)d_in[0];
  const void* mask = d_in[1];
  char* ws = (char*)d_ws;

  ushort* emb_bf = (ushort*)(ws + OFF_EMB);
  float*  x2     = (float*)(ws + OFF_X2);
  float*  ap     = (float*)(ws + OFF_AP);
  int*    flag   = (int*)(ws + OFF_FLAG);
  float*  part   = (float*)(ws + OFF_PART);
  float*  rs     = (float*)(ws + OFF_RS);

  smv2_prep<<<1024, 256, 0, stream>>>(emb, (const uint32_t*)mask, emb_bf, x2, flag);
  smv2_main<<<NTRI, 512, 0, stream>>>(emb_bf, x2, (const uint8_t*)mask, flag, ap, part);
  smv2_rowsum<<<32, 256, 0, stream>>>(part, rs);
  smv2_finalize<<<1, 1024, 0, stream>>>(rs, ap, (float*)d_out);
}

// Round 7
// 441.903 us; speedup vs baseline: 1.1099x; 1.1099x over previous
//
#include <hip/hip_runtime.h>
#include <hip/hip_bf16.h>
#include <stdint.h>

#define TWO_N  8192
#define NHALF  4096
#define DDIM   256
#define MARGIN 0.5f
#define NTRI   2080   // 64*65/2 upper-triangle tile pairs

// ---- workspace layout (bytes) ----
static const size_t OFF_EMB  = 0;                             // 8192*256 bf16 = 4 MB
static const size_t OFF_X2   = 4u * 1024 * 1024;              // 8192 f32 = 32 KB
static const size_t OFF_AP   = OFF_X2 + (size_t)TWO_N * 4;    // 4096 f32 = 16 KB
static const size_t OFF_FLAG = OFF_AP + (size_t)NHALF * 4;    // 1 int (padded)
static const size_t OFF_BITM = 5u * 1024 * 1024;              // 8192*1024 B = 8 MB bitmask
static const size_t OFF_RS   = 13u * 1024 * 1024;             // 8192 f32 = 32 KB

typedef __attribute__((ext_vector_type(8))) short bf16x8;
typedef __attribute__((ext_vector_type(4))) float f32x4;

__device__ inline ushort f2bf(float f) {
  uint32_t u = __float_as_uint(f);
  uint32_t r = (u + 0x7FFFu + ((u >> 16) & 1u)) >> 16;  // RNE
  return (ushort)r;
}
__device__ inline float bf2f(ushort h) { return __uint_as_float((uint32_t)h << 16); }

// async global->LDS; LDS dest = wave-uniform base + lane*size
__device__ inline void gload_lds16(const void* g, void* l) {
  __builtin_amdgcn_global_load_lds(
      (const __attribute__((address_space(1))) uint32_t*)(uintptr_t)g,
      (__attribute__((address_space(3))) uint32_t*)(uint32_t)(uintptr_t)l,
      16, 0, 0);
}
__device__ inline void gload_lds4(const void* g, void* l) {
  __builtin_amdgcn_global_load_lds(
      (const __attribute__((address_space(1))) uint32_t*)(uintptr_t)g,
      (__attribute__((address_space(3))) uint32_t*)(uint32_t)(uintptr_t)l,
      4, 0, 0);
}

// ---------------- prep: bf16 convert + x2 (from bf16 values) + mask-dtype detect ----------------
__global__ __launch_bounds__(256) void smv2_prep(
    const float* __restrict__ emb,
    const uint32_t* __restrict__ maskw,
    ushort* __restrict__ emb_bf,
    float* __restrict__ x2,
    int* __restrict__ flag)
{
  const int t = threadIdx.x;
  if (blockIdx.x == 0) {
    __shared__ int sflag;
    if (t == 0) sflag = 0;
    __syncthreads();
    int found = 0;
    #pragma unroll
    for (int k = 0; k < 8; ++k) {
      uint32_t w = maskw[t * 8 + k];
      if (w > 1u && (w & 0xFEFEFEFEu) == 0u) found = 1;  // bytes in {0,1} => byte mask
    }
    if (found) atomicOr(&sflag, 1);
    __syncthreads();
    if (t == 0) *flag = sflag;
  }
  const int row  = blockIdx.x * 8 + (t >> 5);
  const int lane = t & 31;
  const float* rp = emb + (size_t)row * DDIM + lane * 8;
  float4 v0 = *(const float4*)(rp);
  float4 v1 = *(const float4*)(rp + 4);
  float vals[8] = {v0.x, v0.y, v0.z, v0.w, v1.x, v1.y, v1.z, v1.w};
  uint32_t packed[4];
  float ss = 0.f;
  #pragma unroll
  for (int k = 0; k < 4; ++k) {
    ushort h0 = f2bf(vals[2 * k]);
    ushort h1 = f2bf(vals[2 * k + 1]);
    packed[k] = (uint32_t)h0 | ((uint32_t)h1 << 16);
    float f0 = bf2f(h0), f1 = bf2f(h1);
    ss += f0 * f0 + f1 * f1;
  }
  *(uint4*)(emb_bf + (size_t)row * DDIM + lane * 8) =
      make_uint4(packed[0], packed[1], packed[2], packed[3]);
  #pragma unroll
  for (int m = 1; m < 32; m <<= 1) ss += __shfl_xor(ss, m);
  if (lane == 0) x2[row] = ss;
}

// ---------------- pack: mask (byte or word) -> bit mask (8192 x 1024 B rows); zero rs ------------
__global__ __launch_bounds__(256) void smv2_pack(
    const uint8_t* __restrict__ mask8,
    const int* __restrict__ flagp,
    uint32_t* __restrict__ bitM,
    float* __restrict__ rs)
{
  const int t = threadIdx.x;
  if (blockIdx.x == 0) {            // zero rs: 8192 f32 = 2048 float4
    float4 z = {0.f, 0.f, 0.f, 0.f};
    #pragma unroll
    for (int i = 0; i < 8; ++i) ((float4*)rs)[t * 8 + i] = z;
  }
  const int tid = blockIdx.x * 256 + t;
  const int isByte = *flagp;
  if (isByte) {
    #pragma unroll
    for (int it = 0; it < 4; ++it) {
      const int idx = it * (2048 * 256) + tid;   // u32 output index; 32 mask bytes
      const uint4 a = ((const uint4*)mask8)[(size_t)idx * 2];
      const uint4 b = ((const uint4*)mask8)[(size_t)idx * 2 + 1];
      const uint32_t wsv[8] = {a.x, a.y, a.z, a.w, b.x, b.y, b.z, b.w};
      uint32_t out = 0;
      #pragma unroll
      for (int j = 0; j < 8; ++j)
        out |= ((((wsv[j] & 0x01010101u) * 0x01020408u) >> 24) & 0xFu) << (4 * j);
      bitM[idx] = out;
    }
  } else {
    const uint32_t* maskw = (const uint32_t*)mask8;
    #pragma unroll
    for (int it = 0; it < 4; ++it) {
      const int idx = it * (2048 * 256) + tid;   // 32 mask words
      uint32_t out = 0;
      #pragma unroll
      for (int j = 0; j < 8; ++j) {
        const uint4 wv = ((const uint4*)maskw)[(size_t)idx * 8 + j];
        out |= (wv.x != 0u ? 1u : 0u) << (4 * j);
        out |= (wv.y != 0u ? 1u : 0u) << (4 * j + 1);
        out |= (wv.z != 0u ? 1u : 0u) << (4 * j + 2);
        out |= (wv.w != 0u ? 1u : 0u) << (4 * j + 3);
      }
      bitM[idx] = out;
    }
  }
}

// ---------------- main: symmetric fused Gram -> dist -> exp -> masked row+col partials ----------
// Upper-triangle tile pairs (by<=bx), 512 threads (8 waves 2x4), tile 128x128.
// 8 K-phases of 32, double-buffered A/B; stage(p+1) before compute(p); __syncthreads per phase.
// Mask via bit-pack: M1 tile = 2 KB LDS, M2 = 2 x uint2 regs.
// LDS: 2*(8K+8K) + 2K + 1K = 35 KB -> 4 blocks/CU; __launch_bounds__(512,8) -> VGPR<=64,
// 32 waves/CU (100% occupancy) — TLP hides the per-phase drain.
__global__ __launch_bounds__(512, 8) void smv2_main(
    const ushort* __restrict__ emb_bf,
    const float* __restrict__ x2,
    const uint8_t* __restrict__ bitM,
    float* __restrict__ ap,
    float* __restrict__ rs)
{
  __shared__ char bufA[2 * 8192];
  __shared__ char bufB[2 * 8192];
  __shared__ uint32_t ldsM[512];       // 128 rows x 16 B bit-mask tile
  __shared__ float ldsX[256];          // x2[brow..+128) | x2[bcol..+128)

  const int t = threadIdx.x;

  // XCD chunking (2080 = 8*260) + triangular decode (bx-outer: B panel stable per XCD)
  const int bid = blockIdx.x;
  const int idx = (bid & 7) * (NTRI / 8) + (bid >> 3);
  float rf = sqrtf(8.f * (float)idx + 1.f);
  int bx = (int)((rf - 1.f) * 0.5f);
  while ((bx + 1) * (bx + 2) / 2 <= idx) ++bx;
  while (bx * (bx + 1) / 2 > idx) --bx;
  const int by = idx - bx * (bx + 1) / 2;  // by <= bx
  const int brow = by * 128;
  const int bcol = bx * 128;
  const bool diag = (bx == by);

  const char* gA = (const char*)(emb_bf + (size_t)brow * DDIM);  // 512B rows
  const char* gB = (const char*)(emb_bf + (size_t)bcol * DDIM);

  // ---- hoisted staging addresses ----
  const int srow = t >> 2;                                      // 0..127
  const int scb  = ((t & 3) * 16) ^ (((srow >> 1) & 3) << 4);   // pre-swizzled col
  const size_t gOff = (size_t)srow * 512 + scb;
  const int ldst = t * 16;

  const int w  = t >> 6;
  const int l  = t & 63;
  const int wr = w >> 2;           // wave row 0..1  (64 rows)
  const int wc = w & 3;            // wave col 0..3  (32 cols)
  const int cl = l & 15;
  const int kh = l >> 4;

  // ---- hoisted ds_read offsets (bank-swizzled: ((row>>1)&3)<<4 on 64B rows) ----
  int aoff[4], boff[2];
  #pragma unroll
  for (int m = 0; m < 4; ++m) {
    const int row = wr * 64 + m * 16 + cl;
    aoff[m] = row * 64 + ((kh * 16) ^ (((row >> 1) & 3) << 4));
  }
  #pragma unroll
  for (int n = 0; n < 2; ++n) {
    const int row = wc * 32 + n * 16 + cl;
    boff[n] = row * 64 + ((kh * 16) ^ (((row >> 1) & 3) << 4));
  }

  f32x4 acc[4][2];
  #pragma unroll
  for (int m = 0; m < 4; ++m)
    #pragma unroll
    for (int n = 0; n < 2; ++n) {
      f32x4 z = {0.f, 0.f, 0.f, 0.f};
      acc[m][n] = z;
    }

  // ---- M2 (mirror mask) to registers: 64 bits of row gj covering cols [brow+wr*64, +64) ----
  uint2 m2[2];
  #pragma unroll
  for (int n = 0; n < 2; ++n) {
    const int gj = bcol + wc * 32 + n * 16 + cl;
    m2[n] = *(const uint2*)(bitM + (size_t)gj * 1024 + (brow >> 3) + wr * 8);
  }
  __builtin_amdgcn_sched_barrier(0);

  // ---- M1 bit tile (2 KB): 128 rows x 16 B; all 512 threads load 4 B ----
  gload_lds4(bitM + (size_t)(brow + srow) * 1024 + (bcol >> 3) + (t & 3) * 4,
             (char*)ldsM + t * 4);
  // ---- x2 slices (1 KB): 256 f32, threads 256..511 duplicate (benign) ----
  {
    const int xi = t & 255;
    const float* src = (xi < 128) ? (x2 + brow + xi) : (x2 + bcol + (xi - 128));
    gload_lds4(src, (char*)ldsX + xi * 4);
  }
  // ---- stage K-phase 0 ----
  gload_lds16(gA + gOff, bufA + ldst);
  gload_lds16(gB + gOff, bufB + ldst);
  __syncthreads();

#define STAGE(Q)                                                            \
  {                                                                         \
    gload_lds16(gA + gOff + (Q) * 64, bufA + ((Q) & 1) * 8192 + ldst);      \
    gload_lds16(gB + gOff + (Q) * 64, bufB + ((Q) & 1) * 8192 + ldst);      \
  }

#define COMPUTE(P)                                                          \
  {                                                                         \
    const char* ba = bufA + ((P) & 1) * 8192;                               \
    const char* bb = bufB + ((P) & 1) * 8192;                               \
    bf16x8 a0 = *(const bf16x8*)(ba + aoff[0]);                             \
    bf16x8 a1 = *(const bf16x8*)(ba + aoff[1]);                             \
    bf16x8 a2 = *(const bf16x8*)(ba + aoff[2]);                             \
    bf16x8 a3 = *(const bf16x8*)(ba + aoff[3]);                             \
    bf16x8 b0 = *(const bf16x8*)(bb + boff[0]);                             \
    bf16x8 b1 = *(const bf16x8*)(bb + boff[1]);                             \
    acc[0][0] = __builtin_amdgcn_mfma_f32_16x16x32_bf16(a0, b0, acc[0][0], 0, 0, 0); \
    acc[0][1] = __builtin_amdgcn_mfma_f32_16x16x32_bf16(a0, b1, acc[0][1], 0, 0, 0); \
    acc[1][0] = __builtin_amdgcn_mfma_f32_16x16x32_bf16(a1, b0, acc[1][0], 0, 0, 0); \
    acc[1][1] = __builtin_amdgcn_mfma_f32_16x16x32_bf16(a1, b1, acc[1][1], 0, 0, 0); \
    acc[2][0] = __builtin_amdgcn_mfma_f32_16x16x32_bf16(a2, b0, acc[2][0], 0, 0, 0); \
    acc[2][1] = __builtin_amdgcn_mfma_f32_16x16x32_bf16(a2, b1, acc[2][1], 0, 0, 0); \
    acc[3][0] = __builtin_amdgcn_mfma_f32_16x16x32_bf16(a3, b0, acc[3][0], 0, 0, 0); \
    acc[3][1] = __builtin_amdgcn_mfma_f32_16x16x32_bf16(a3, b1, acc[3][1], 0, 0, 0); \
  }

#define PHASE(P)                                                            \
  {                                                                         \
    if ((P) < 7) STAGE((P) + 1);                                            \
    __builtin_amdgcn_sched_barrier(0);                                      \
    COMPUTE(P);                                                             \
    __syncthreads();                                                        \
  }

  PHASE(0) PHASE(1) PHASE(2) PHASE(3) PHASE(4) PHASE(5) PHASE(6) PHASE(7)

  // ---- epilogue ----
  float* part  = (float*)bufA;   // [4][128] row-side partials (buf0 region; last compute used buf1)
  float* part2 = (float*)bufB;   // [2][128] col-side partials
  float cs[2] = {0.f, 0.f};

  #pragma unroll
  for (int m = 0; m < 4; ++m) {
    #pragma unroll
    for (int q = 0; q < 4; ++q) {
      const int lrow = wr * 64 + m * 16 + kh * 4 + q;  // C/D: row = (l>>4)*4 + reg
      const int gi = brow + lrow;
      const float xi = ldsX[lrow];
      const uint32_t m1w = ldsM[lrow * 4 + wc];        // bits for cols [wc*32, +32)
      float rp = 0.f;
      #pragma unroll
      for (int n = 0; n < 2; ++n) {
        const int jc = wc * 32 + n * 16 + cl;
        const int gj = bcol + jc;
        const float g = acc[m][n][q];
        float sq = (gi == gj) ? 0.f : (xi + ldsX[128 + jc] - 2.f * g);
        sq = fmaxf(sq, 0.f) + 1e-12f;
        const float dd = __builtin_amdgcn_sqrtf(sq);
        if (gj == gi + NHALF && gi < NHALF) ap[gi] = dd;  // anchor-positive distance
        const float e = __expf(MARGIN - dd);
        const uint32_t mk1 = (m1w >> (n * 16 + cl)) & 1u;
        rp += mk1 ? e : 0.f;
        const uint32_t m2bits = (m < 2) ? m2[n].x : m2[n].y;
        const uint32_t mk2 = (m2bits >> ((m & 1) * 16 + kh * 4 + q)) & 1u;
        cs[n] += mk2 ? e : 0.f;
      }
      #pragma unroll
      for (int s = 1; s < 16; s <<= 1) rp += __shfl_xor(rp, s);
      if (cl == 0) part[wc * 128 + lrow] = rp;
    }
  }

  #pragma unroll
  for (int n = 0; n < 2; ++n) {
    cs[n] += __shfl_xor(cs[n], 16);   // reduce over kh
    cs[n] += __shfl_xor(cs[n], 32);
    if (l < 16) part2[wr * 128 + wc * 32 + n * 16 + l] = cs[n];
  }
  __syncthreads();

  if (t < 128) {
    atomicAdd(&rs[brow + t],
              (part[t] + part[128 + t]) + (part[256 + t] + part[384 + t]));
    if (!diag)
      atomicAdd(&rs[bcol + t], part2[t] + part2[128 + t]);
  }
#undef PHASE
#undef COMPUTE
#undef STAGE
}

// ---------------- finalize: j = log(rs[i]+rs[i+N]) + ap[i]; loss ----------------
__global__ __launch_bounds__(1024) void smv2_finalize(
    const float* __restrict__ rs, const float* __restrict__ ap,
    float* __restrict__ out)
{
  const int t = threadIdx.x;
  float sum = 0.f, cnt = 0.f;
  for (int i = t; i < NHALF; i += 1024) {
    float rsum = rs[i] + rs[i + NHALF];
    float jv = logf(rsum) + ap[i];
    if (!isnan(jv)) {
      cnt += 1.f;
      float mj = fmaxf(jv, 0.f);
      sum += mj * mj;
    }
  }
  __shared__ float ssum[16], scnt[16];
  #pragma unroll
  for (int s = 32; s >= 1; s >>= 1) {
    sum += __shfl_down(sum, s);
    cnt += __shfl_down(cnt, s);
  }
  const int wid = t >> 6, lid = t & 63;
  if (lid == 0) { ssum[wid] = sum; scnt[wid] = cnt; }
  __syncthreads();
  if (t == 0) {
    float S = 0.f, C = 0.f;
    #pragma unroll
    for (int i = 0; i < 16; ++i) { S += ssum[i]; C += scnt[i]; }
    if (C < 1.f) C = 1.f;
    out[0] = S / C * 0.5f;
  }
}

extern "C" void kernel_launch(void* const* d_in, const int* in_sizes, int n_in,
                              void* d_out, int out_size, void* d_ws, size_t ws_size,
                              hipStream_t stream) {
  const float* emb = (const float*)d_in[0];
  const void* mask = d_in[1];
  char* ws = (char*)d_ws;

  ushort*   emb_bf = (ushort*)(ws + OFF_EMB);
  float*    x2     = (float*)(ws + OFF_X2);
  float*    ap     = (float*)(ws + OFF_AP);
  int*      flag   = (int*)(ws + OFF_FLAG);
  uint32_t* bitM   = (uint32_t*)(ws + OFF_BITM);
  float*    rs     = (float*)(ws + OFF_RS);

  smv2_prep<<<1024, 256, 0, stream>>>(emb, (const uint32_t*)mask, emb_bf, x2, flag);
  smv2_pack<<<2048, 256, 0, stream>>>((const uint8_t*)mask, flag, bitM, rs);
  smv2_main<<<NTRI, 512, 0, stream>>>(emb_bf, x2, (const uint8_t*)bitM, ap, rs);
  smv2_finalize<<<1, 1024, 0, stream>>>(rs, ap, (float*)d_out);
}